// Round 1
// baseline (643.135 us; speedup 1.0000x reference)
//
#include <hip/hip_runtime.h>
#include <math.h>

#define HID   64
#define OUTC  40
#define CAP   64   // max in-degree bucket capacity (Poisson(16): P(overflow) ~ 1e-13)

// ---------------- degree histogram ----------------
__global__ void deg_kernel(const int* __restrict__ dst, int* __restrict__ cnt, int E) {
    int e = blockIdx.x * blockDim.x + threadIdx.x;
    if (e < E) atomicAdd(&cnt[dst[e]], 1);
}

// dinv = rsqrt(deg+1); reset cnt for reuse as fill cursor
__global__ void dinv_kernel(int* __restrict__ cnt, float* __restrict__ dinv, int N) {
    int i = blockIdx.x * blockDim.x + threadIdx.x;
    if (i < N) {
        dinv[i] = rsqrtf((float)cnt[i] + 1.0f);
        cnt[i] = 0;
    }
}

// bucket fill: recs[dst][slot] = (src, enorm)
__global__ void fill_kernel(const int* __restrict__ src, const int* __restrict__ dst,
                            const float* __restrict__ dinv, int* __restrict__ cnt,
                            int2* __restrict__ recs, int E) {
    int e = blockIdx.x * blockDim.x + threadIdx.x;
    if (e < E) {
        int s = src[e], d = dst[e];
        float en = dinv[s] * dinv[d];
        int pos = atomicAdd(&cnt[d], 1);
        if (pos < CAP) recs[(size_t)d * CAP + pos] = make_int2(s, __float_as_int(en));
    }
}

// ---------------- dense transform: out[N,64] = X[N,CIN] @ W[CIN,64] ----------------
template<int CIN>
__global__ void gemm_kernel(const float* __restrict__ X, const float* __restrict__ W,
                            float* __restrict__ out, int N) {
    int lane = threadIdx.x & 63;
    int row  = (blockIdx.x << 2) + (threadIdx.x >> 6);
    if (row >= N) return;
    const float* xr = X + (size_t)row * CIN;
    float xv[CIN / 64];
    #pragma unroll
    for (int j = 0; j < CIN / 64; j++) xv[j] = xr[j * 64 + lane];
    float acc = 0.f;
    #pragma unroll
    for (int j = 0; j < CIN / 64; j++) {
        #pragma unroll
        for (int k = 0; k < 64; k++)
            acc = fmaf(__shfl(xv[j], k), W[(size_t)(j * 64 + k) * HID + lane], acc);
    }
    out[(size_t)row * HID + lane] = acc;
}

// ---------------- gather-aggregate + self-loop + bias (+ LN + ReLU) ----------------
template<bool LN>
__global__ void conv_kernel(const float* __restrict__ hw, const int2* __restrict__ recs,
                            const int* __restrict__ cnt, const float* __restrict__ dinv,
                            const float* __restrict__ b, const float* __restrict__ g,
                            const float* __restrict__ be, float* __restrict__ out, int N) {
    int lane = threadIdx.x & 63;
    int row  = (blockIdx.x << 2) + (threadIdx.x >> 6);
    if (row >= N) return;

    int c = cnt[row];
    if (c > CAP) c = CAP;

    // lane-parallel preload of this node's edge records, broadcast via shfl
    int2 myrec = make_int2(0, 0);
    if (lane < c) myrec = recs[(size_t)row * CAP + lane];

    float acc = 0.f;
    for (int k = 0; k < c; k++) {
        int   s  = __shfl(myrec.x, k);
        float en = __shfl(__int_as_float(myrec.y), k);
        acc = fmaf(en, hw[(size_t)s * HID + lane], acc);
    }
    float di = dinv[row];
    acc = fmaf(di * di, hw[(size_t)row * HID + lane], acc) + b[lane];

    if (LN) {
        float s = acc;
        #pragma unroll
        for (int o = 32; o; o >>= 1) s += __shfl_xor(s, o);
        float mu = s * (1.f / 64.f);
        float d0 = acc - mu;
        float v  = d0 * d0;
        #pragma unroll
        for (int o = 32; o; o >>= 1) v += __shfl_xor(v, o);
        v *= (1.f / 64.f);
        acc = d0 * rsqrtf(v + 1e-5f) * g[lane] + be[lane];
        acc = fmaxf(acc, 0.f);
    }
    out[(size_t)row * HID + lane] = acc;
}

// ---------------- MLP (64->64 relu ->40) + softmax, one wave per node ----------------
__global__ void mlp_kernel(const float* __restrict__ h,
                           const float* __restrict__ M1, const float* __restrict__ mb1,
                           const float* __restrict__ M2, const float* __restrict__ mb2,
                           float* __restrict__ out, int N) {
    __shared__ float sM1[HID * HID];
    __shared__ float sM2[HID * OUTC + 64];  // padded: lanes >= OUTC read garbage, masked later
    __shared__ float sb1[HID];
    __shared__ float sb2[HID];

    int t = threadIdx.x;
    for (int i = t; i < HID * HID; i += 256) sM1[i] = M1[i];
    for (int i = t; i < HID * OUTC; i += 256) sM2[i] = M2[i];
    if (t < HID)  sb1[t] = mb1[t];
    if (t < HID)  sb2[t] = (t < OUTC) ? mb2[t] : 0.f;
    __syncthreads();

    int lane = t & 63, w = t >> 6;
    for (int base = blockIdx.x * 4 + w; base < N; base += gridDim.x * 4) {
        int row = base;
        float hv = h[(size_t)row * HID + lane];

        // layer M1 + relu
        float acc = sb1[lane];
        #pragma unroll
        for (int k = 0; k < HID; k++)
            acc = fmaf(__shfl(hv, k), sM1[k * HID + lane], acc);
        float hr = fmaxf(acc, 0.f);

        // layer M2 (lanes >= OUTC compute garbage from padded LDS, masked below)
        float o = sb2[lane];
        #pragma unroll
        for (int k = 0; k < HID; k++)
            o = fmaf(__shfl(hr, k), sM2[k * OUTC + lane], o);

        float logit = (lane < OUTC) ? o : -INFINITY;
        float mx = logit;
        #pragma unroll
        for (int s = 32; s; s >>= 1) mx = fmaxf(mx, __shfl_xor(mx, s));
        float e = (lane < OUTC) ? expf(logit - mx) : 0.f;
        float sum = e;
        #pragma unroll
        for (int s = 32; s; s >>= 1) sum += __shfl_xor(sum, s);
        if (lane < OUTC) out[(size_t)row * OUTC + lane] = e / sum;
    }
}

extern "C" void kernel_launch(void* const* d_in, const int* in_sizes, int n_in,
                              void* d_out, int out_size, void* d_ws, size_t ws_size,
                              hipStream_t stream) {
    const float* x   = (const float*)d_in[0];
    const int*   ei  = (const int*)  d_in[1];
    const float* W1  = (const float*)d_in[2];
    const float* b1  = (const float*)d_in[3];
    const float* W2  = (const float*)d_in[4];
    const float* b2  = (const float*)d_in[5];
    const float* W3  = (const float*)d_in[6];
    const float* b3  = (const float*)d_in[7];
    const float* g1  = (const float*)d_in[8];
    const float* be1 = (const float*)d_in[9];
    const float* g2  = (const float*)d_in[10];
    const float* be2 = (const float*)d_in[11];
    const float* M1  = (const float*)d_in[12];
    const float* mb1 = (const float*)d_in[13];
    const float* M2  = (const float*)d_in[14];
    const float* mb2 = (const float*)d_in[15];

    const int IN_C = 128;
    int N = in_sizes[0] / IN_C;
    int E = in_sizes[1] / 2;
    const int* src = ei;
    const int* dst = ei + E;

    // workspace carve-up
    char* ws = (char*)d_ws;
    size_t off = 0;
    auto carve = [&](size_t bytes) -> void* {
        void* p = ws + off;
        off = (off + bytes + 255) & ~(size_t)255;
        return p;
    };
    int*   cnt  = (int*)  carve((size_t)N * sizeof(int));
    float* dinv = (float*)carve((size_t)N * sizeof(float));
    int2*  recs = (int2*) carve((size_t)N * CAP * sizeof(int2));
    float* HW   = (float*)carve((size_t)N * HID * sizeof(float));
    float* H    = (float*)carve((size_t)N * HID * sizeof(float));

    hipMemsetAsync(cnt, 0, (size_t)N * sizeof(int), stream);

    int eb = (E + 255) / 256;
    int nb = (N + 255) / 256;
    int rb = (N + 3) / 4;  // one wave (64 lanes) per node, 4 waves per block

    deg_kernel <<<eb, 256, 0, stream>>>(dst, cnt, E);
    dinv_kernel<<<nb, 256, 0, stream>>>(cnt, dinv, N);
    fill_kernel<<<eb, 256, 0, stream>>>(src, dst, dinv, cnt, recs, E);

    // layer 1
    gemm_kernel<128><<<rb, 256, 0, stream>>>(x, W1, HW, N);
    conv_kernel<true><<<rb, 256, 0, stream>>>(HW, recs, cnt, dinv, b1, g1, be1, H, N);
    // layer 2
    gemm_kernel<64><<<rb, 256, 0, stream>>>(H, W2, HW, N);
    conv_kernel<true><<<rb, 256, 0, stream>>>(HW, recs, cnt, dinv, b2, g2, be2, H, N);
    // layer 3 (no LN/ReLU)
    gemm_kernel<64><<<rb, 256, 0, stream>>>(H, W3, HW, N);
    conv_kernel<false><<<rb, 256, 0, stream>>>(HW, recs, cnt, dinv, b3, nullptr, nullptr, H, N);

    // MLP + softmax
    mlp_kernel<<<2048, 256, 0, stream>>>(H, M1, mb1, M2, mb2, (float*)d_out, N);
}